// Round 20
// baseline (230.206 us; speedup 1.0000x reference)
//
#include <hip/hip_runtime.h>
#include <cstdint>

using u16 = unsigned short;
using u32 = unsigned int;
typedef __bf16 bf16x8 __attribute__((ext_vector_type(8)));
typedef float f32x4 __attribute__((ext_vector_type(4)));
typedef float f32x16 __attribute__((ext_vector_type(16)));
typedef u16 u16x8 __attribute__((ext_vector_type(8)));
typedef u16 u16x4 __attribute__((ext_vector_type(4)));

#define DEV static __device__ __forceinline__

DEV u16 f2bf(float f) {
  uint32_t u = __builtin_bit_cast(uint32_t, f);
  u += 0x7FFFu + ((u >> 16) & 1u);
  return (u16)(u >> 16);
}
DEV float bf2f(u16 h) {
  uint32_t u = ((uint32_t)h) << 16;
  return __builtin_bit_cast(float, u);
}
DEV u32 cvt_pk_bf16(float lo, float hi) {  // attn only (T12 pattern)
  u32 r;
  asm("v_cvt_pk_bf16_f32 %0, %1, %2" : "=v"(r) : "v"(lo), "v"(hi));
  return r;
}

typedef const u32 __attribute__((address_space(1))) gcu32;
typedef u32 __attribute__((address_space(3))) lu32;
DEV void gl_lds16(const u16* g, u16* l) {
  __builtin_amdgcn_global_load_lds((gcu32*)g, (lu32*)l, 16, 0, 0);
}

#define MFMA(a, b, c) __builtin_amdgcn_mfma_f32_16x16x32_bf16((a), (b), (c), 0, 0, 0)
#define MFMA32(a, b, c) __builtin_amdgcn_mfma_f32_32x32x16_bf16((a), (b), (c), 0, 0, 0)

#define WAITV(n) asm volatile("s_waitcnt vmcnt(" #n ")" ::: "memory")

// ---------------------------------------------------------------------------
// Fused conversion pass: f32 -> bf16 once, outside the GEMM hot loops.
// ---------------------------------------------------------------------------
__global__ __launch_bounds__(256) void cvt_all(
    const float* __restrict__ q, const float* __restrict__ k,
    const float* __restrict__ v, const float* __restrict__ Wq,
    const float* __restrict__ Wk, const float* __restrict__ Wv,
    const float* __restrict__ Wo, u16* __restrict__ Xb, u16* __restrict__ Wb,
    u16* __restrict__ WoB) {
  const int bid = blockIdx.x;
  const float* src;
  u16* dst;
  size_t i;
  if (bid < 12288) {
    const int z = bid >> 12;
    src = (z == 0) ? q : (z == 1) ? k : v;
    dst = Xb + (size_t)z * 8388608;
    i = ((size_t)(bid & 4095) * 256 + threadIdx.x) * 8;
  } else {
    const int r = bid - 12288;
    const int z = r >> 9;
    src = (z == 0) ? Wq : (z == 1) ? Wk : (z == 2) ? Wv : Wo;
    dst = (z < 3) ? (Wb + (size_t)z * 1048576) : WoB;
    i = ((size_t)(r & 511) * 256 + threadIdx.x) * 8;
  }
  const float4 a = *(const float4*)(src + i);
  const float4 b = *(const float4*)(src + i + 4);
  u16x8 o;
  o[0] = f2bf(a.x); o[1] = f2bf(a.y); o[2] = f2bf(a.z); o[3] = f2bf(a.w);
  o[4] = f2bf(b.x); o[5] = f2bf(b.y); o[6] = f2bf(b.z); o[7] = f2bf(b.w);
  *(u16x8*)(dst + i) = o;
}

// ---------------------------------------------------------------------------
// Pure-bf16 fused projection GEMM. R20: m201-style phase-split template.
// BM=BN=256, BK=64, 512 threads, 8 waves (2m x 4n), per-wave output 128x64
// (acc[8][4]) -- raises flop/LDS-byte 32 -> 42.7 and halves staging writes
// per flop (1 block/CU). This attacks the MEASURED binder: at 64x64 wave
// tiles the LDS pipe costs ~3-5x the MFMA cycles (MfmaUtil stuck at 26%
// across R10-R19 while conflicts/latency/fetch were each eliminated).
// Schedule per K-tile: issue 8 gl_lds of t+1 -> WAITV(8) (counted; loads had
// a full tile ~600cyc to land) -> barrier -> 4 phases {ds_read frags ->
// barrier -> setprio + 16 MFMA + setprio -> barrier} split by (kk, n-pair);
// a-frags (kk-slice, 32 VGPR) reused across the 2 n-pair phases. The phase
// barriers keep waves role-split (T3/T5 regime). LDS dbuf 128KB.
// Staging/read swizzle = R10-verified formulas (conflicts=0; row&7 XOR
// invariants hold for BM=256). Grid (32m,4n,3z): XCD = m%8. z = 0:Q,1:K,2:V.
// Output bf16: z<2 -> out[(b*16+h)*2048+s][d]; z=2 -> out[(b*16+h)*64+d][s].
// Q epilogue folds oscale = (1/8)*log2(e) (attn works in log2 domain).
// ---------------------------------------------------------------------------
__global__ __launch_bounds__(512, 2) void proj_gemm_bf(
    const u16* __restrict__ Xb, const u16* __restrict__ Wb,
    const float* __restrict__ bq, const float* __restrict__ bk,
    const float* __restrict__ bv, u16* __restrict__ Qh, u16* __restrict__ Kh,
    u16* __restrict__ Vt) {
  __shared__ u16 As[2][256 * 64];  // 2 x 32KB
  __shared__ u16 Bs[2][256 * 64];  // 2 x 32KB
  const int z = blockIdx.z;
  const int m0 = blockIdx.x * 256, n0 = blockIdx.y * 256;

  const u16* x = Xb + (size_t)z * 8388608;
  const u16* W = Wb + (size_t)z * 1048576;
  const float* bias = (z == 0) ? bq : (z == 1) ? bk : bv;
  u16* out = (z == 0) ? Qh : (z == 1) ? Kh : Vt;
  const float oscale = (z == 0) ? 0.18033688011112042f : 1.0f;

  const int tid = threadIdx.x;
  const int w = tid >> 6, lane = tid & 63;
  const int wr = w >> 2, wc = w & 3;  // 2m x 4n waves
  const int lr = lane & 15, hq = lane >> 4;

  // staging (R10-verified): load l covers rows l*64 + w*8 + (lane>>3);
  // LDS dest linear (wave-uniform base + lane*16B); global source chunk
  // pre-swizzled (chunk = (lane&7) ^ ((lane>>3)&7) = (lane&7) ^ (row&7)).
  const int scol = ((lane & 7) ^ ((lane >> 3) & 7)) * 8;
  const u16* xg = x + (size_t)(m0 + w * 8 + (lane >> 3)) * 1024 + scol;
  const u16* wg_ = W + (size_t)(n0 + w * 8 + (lane >> 3)) * 1024 + scol;

  f32x4 acc[8][4];
  const f32x4 fzero = {0.f, 0.f, 0.f, 0.f};
#pragma unroll
  for (int m = 0; m < 8; ++m)
#pragma unroll
    for (int n = 0; n < 4; ++n) acc[m][n] = fzero;

#define PSTAGE(b, t)                                                          \
  {                                                                           \
    _Pragma("unroll") for (int l = 0; l < 4; ++l)                             \
      gl_lds16(xg + (size_t)l * 64 * 1024 + (t) * 64,                         \
               &As[b][(l * 64 + w * 8) * 64]);                                \
    _Pragma("unroll") for (int l = 0; l < 4; ++l)                             \
      gl_lds16(wg_ + (size_t)l * 64 * 1024 + (t) * 64,                        \
               &Bs[b][(l * 64 + w * 8) * 64]);                                \
  }
#define RCH(kk) ((((kk) * 4 + hq) ^ (lr & 7)) * 8)

  PSTAGE(0, 0);

#pragma unroll 1
  for (int t = 0; t < 16; ++t) {
    const int cur = t & 1;
    if (t < 15) {
      PSTAGE(cur ^ 1, t + 1);
      WAITV(8);  // retires exactly tile t's 8 loads (oldest in FIFO)
    } else {
      WAITV(0);
    }
    __builtin_amdgcn_s_barrier();

    bf16x8 a[8];
#pragma unroll
    for (int kk = 0; kk < 2; ++kk) {
      // phase A (n-pair 0): read a-slice for this kk + b0,b1
#pragma unroll
      for (int m = 0; m < 8; ++m)
        a[m] = *(const bf16x8*)&As[cur][(wr * 128 + m * 16 + lr) * 64 + RCH(kk)];
      {
        const bf16x8 b0 =
            *(const bf16x8*)&Bs[cur][(wc * 64 + 0 * 16 + lr) * 64 + RCH(kk)];
        const bf16x8 b1 =
            *(const bf16x8*)&Bs[cur][(wc * 64 + 1 * 16 + lr) * 64 + RCH(kk)];
        __builtin_amdgcn_s_barrier();
        __builtin_amdgcn_s_setprio(1);
#pragma unroll
        for (int m = 0; m < 8; ++m) {
          acc[m][0] = MFMA(a[m], b0, acc[m][0]);
          acc[m][1] = MFMA(a[m], b1, acc[m][1]);
        }
        __builtin_amdgcn_s_setprio(0);
        __builtin_amdgcn_s_barrier();
      }
      // phase B (n-pair 1): b2,b3 (a-slice reused)
      {
        const bf16x8 b2 =
            *(const bf16x8*)&Bs[cur][(wc * 64 + 2 * 16 + lr) * 64 + RCH(kk)];
        const bf16x8 b3 =
            *(const bf16x8*)&Bs[cur][(wc * 64 + 3 * 16 + lr) * 64 + RCH(kk)];
        __builtin_amdgcn_s_barrier();
        __builtin_amdgcn_s_setprio(1);
#pragma unroll
        for (int m = 0; m < 8; ++m) {
          acc[m][2] = MFMA(a[m], b2, acc[m][2]);
          acc[m][3] = MFMA(a[m], b3, acc[m][3]);
        }
        __builtin_amdgcn_s_setprio(0);
        __builtin_amdgcn_s_barrier();
      }
    }
  }
#undef PSTAGE
#undef RCH

#pragma unroll
  for (int n = 0; n < 4; ++n) {
    const int col = n0 + wc * 64 + n * 16 + lr;
    const float bvv = bias[col];
    const int h = col >> 6, d = col & 63;
#pragma unroll
    for (int m = 0; m < 8; ++m) {
#pragma unroll
      for (int j = 0; j < 4; ++j) {
        const int rowg = m0 + wr * 128 + m * 16 + hq * 4 + j;
        const int bb = rowg >> 11, s = rowg & 2047;
        const float val = (acc[m][n][j] + bvv) * oscale;
        size_t idx;
        if (z != 2)
          idx = ((size_t)(bb * 16 + h) * 2048 + s) * 64 + d;
        else
          idx = ((size_t)(bb * 16 + h) * 64 + d) * 2048 + s;
        out[idx] = f2bf(val);
      }
    }
  }
}

// ---------------------------------------------------------------------------
// FALLBACK projection GEMM (f32 inputs, barrier staging). Used only when
// ws_size is too small for the bf16 conversion workspace.
// ---------------------------------------------------------------------------
__global__ __launch_bounds__(256) void proj_gemm_f32(
    const float* __restrict__ q, const float* __restrict__ k,
    const float* __restrict__ v, const float* __restrict__ Wq,
    const float* __restrict__ Wk, const float* __restrict__ Wv,
    const float* __restrict__ bq, const float* __restrict__ bk,
    const float* __restrict__ bv, u16* __restrict__ Qh, u16* __restrict__ Kh,
    u16* __restrict__ Vt) {
  __shared__ u16 As[128][40];
  __shared__ u16 Bs[128][40];
  const int z = blockIdx.z;
  const float* x = (z == 0) ? q : (z == 1) ? k : v;
  const float* W = (z == 0) ? Wq : (z == 1) ? Wk : Wv;
  const float* bias = (z == 0) ? bq : (z == 1) ? bk : bv;
  u16* out = (z == 0) ? Qh : (z == 1) ? Kh : Vt;
  const float oscale = (z == 0) ? 0.18033688011112042f : 1.0f;

  const int tid = threadIdx.x;
  const int m0 = blockIdx.y * 128, n0 = blockIdx.x * 128;
  const int w = tid >> 6, lane = tid & 63;
  const int wr = w >> 1, wc = w & 1;
  const int lr = lane & 15, lk = (lane >> 4) * 8;
  const int srow = tid >> 3, sc4 = (tid & 7) * 4;

  f32x4 acc[4][4];
  const f32x4 fzero = {0.f, 0.f, 0.f, 0.f};
#pragma unroll
  for (int m = 0; m < 4; ++m)
#pragma unroll
    for (int n = 0; n < 4; ++n) acc[m][n] = fzero;

  for (int kt = 0; kt < 32; ++kt) {
    const int k0 = kt * 32;
    __syncthreads();
#pragma unroll
    for (int c = 0; c < 4; ++c) {
      const float4 av = *(const float4*)(x + (size_t)(m0 + c * 32 + srow) * 1024 + k0 + sc4);
      const float4 bvv = *(const float4*)(W + (size_t)(n0 + c * 32 + srow) * 1024 + k0 + sc4);
      u16x4 ah, bh;
      ah[0] = f2bf(av.x); ah[1] = f2bf(av.y); ah[2] = f2bf(av.z); ah[3] = f2bf(av.w);
      bh[0] = f2bf(bvv.x); bh[1] = f2bf(bvv.y); bh[2] = f2bf(bvv.z); bh[3] = f2bf(bvv.w);
      *(u16x4*)&As[c * 32 + srow][sc4] = ah;
      *(u16x4*)&Bs[c * 32 + srow][sc4] = bh;
    }
    __syncthreads();
    bf16x8 a[4], b[4];
#pragma unroll
    for (int m = 0; m < 4; ++m)
      a[m] = *(const bf16x8*)&As[wr * 64 + m * 16 + lr][lk];
#pragma unroll
    for (int n = 0; n < 4; ++n)
      b[n] = *(const bf16x8*)&Bs[wc * 64 + n * 16 + lr][lk];
#pragma unroll
    for (int m = 0; m < 4; ++m)
#pragma unroll
      for (int n = 0; n < 4; ++n) acc[m][n] = MFMA(a[m], b[n], acc[m][n]);
  }

#pragma unroll
  for (int n = 0; n < 4; ++n) {
    const int col = n0 + wc * 64 + n * 16 + lr;
    const float bvv = bias[col];
    const int h = col >> 6, d = col & 63;
#pragma unroll
    for (int m = 0; m < 4; ++m) {
#pragma unroll
      for (int j = 0; j < 4; ++j) {
        const int rowg = m0 + wr * 64 + m * 16 + (lane >> 4) * 4 + j;
        const int bb = rowg >> 11, s = rowg & 2047;
        const float val = (acc[m][n][j] + bvv) * oscale;
        size_t idx;
        if (z != 2)
          idx = ((size_t)(bb * 16 + h) * 2048 + s) * 64 + d;
        else
          idx = ((size_t)(bb * 16 + h) * 64 + d) * 2048 + s;
        out[idx] = f2bf(val);
      }
    }
  }
}

// ---------------------------------------------------------------------------
// Flash attention (R15-proven): KVBLK=128, no osum MFMA (row-sum on VALU,
// lane-local by q=lq, one shfl_xor(32) after the KV loop). PV output
// o0[r] = D[q=crow(r,h)][d=lq]; per-row 1/sum via __shfl(linv, qr).
// 8 waves x 32 q-rows = 256 q per block. Output bf16 [b*2048+s][h*64+d].
// ---------------------------------------------------------------------------
__global__ __launch_bounds__(512, 4) void attn_fwd(
    const u16* __restrict__ Qh, const u16* __restrict__ Kh,
    const u16* __restrict__ Vt, u16* __restrict__ Att) {
  __shared__ u16 Ks[128][72];   // K rows (kv), 64 d + pad
  __shared__ u16 Vs[64][136];   // V^T: d rows, 128 s + pad
  const int tid = threadIdx.x;
  const int w = tid >> 6, lane = tid & 63;
  const int lq = lane & 31, h = lane >> 5;
  const int head = blockIdx.x, q0 = blockIdx.y * 256;
  const u16* Qb = Qh + (size_t)head * 131072;
  const u16* Kb = Kh + (size_t)head * 131072;
  const u16* Vb = Vt + (size_t)head * 131072;
  const int qrow = q0 + w * 32 + lq;

  bf16x8 qf[4];
#pragma unroll
  for (int dc = 0; dc < 4; ++dc)
    qf[dc] = *(const bf16x8*)(Qb + (size_t)qrow * 64 + dc * 16 + h * 8);

  f32x16 o0 = {}, o1 = {};
  float lsum = 0.f;

  const int srow = tid >> 3, scol = (tid & 7) * 8;
  uint4 kr0, kr1, vr0, vr1;
  kr0 = *(const uint4*)(Kb + (size_t)srow * 64 + scol);
  kr1 = *(const uint4*)(Kb + (size_t)(64 + srow) * 64 + scol);
  vr0 = *(const uint4*)(Vb + (size_t)srow * 2048 + scol);
  vr1 = *(const uint4*)(Vb + (size_t)srow * 2048 + 64 + scol);

  for (int kt = 0; kt < 16; ++kt) {
    __syncthreads();
    *(uint4*)&Ks[srow][scol] = kr0;
    *(uint4*)&Ks[64 + srow][scol] = kr1;
    *(uint4*)&Vs[srow][scol] = vr0;
    *(uint4*)&Vs[srow][64 + scol] = vr1;
    __syncthreads();
    if (kt + 1 < 16) {
      const int t0n = (kt + 1) * 128;
      kr0 = *(const uint4*)(Kb + (size_t)(t0n + srow) * 64 + scol);
      kr1 = *(const uint4*)(Kb + (size_t)(t0n + 64 + srow) * 64 + scol);
      vr0 = *(const uint4*)(Vb + (size_t)srow * 2048 + t0n + scol);
      vr1 = *(const uint4*)(Vb + (size_t)srow * 2048 + t0n + 64 + scol);
    }

#pragma unroll
    for (int half = 0; half < 2; ++half) {
      const int ko = half * 64;

      f32x16 s0 = {}, s1 = {};
      __builtin_amdgcn_s_setprio(1);
#pragma unroll
      for (int dc = 0; dc < 4; ++dc) {
        const bf16x8 k0 = *(const bf16x8*)&Ks[ko + lq][dc * 16 + h * 8];
        const bf16x8 k1 = *(const bf16x8*)&Ks[ko + 32 + lq][dc * 16 + h * 8];
        s0 = MFMA32(k0, qf[dc], s0);
        s1 = MFMA32(k1, qf[dc], s1);
      }
      __builtin_amdgcn_s_setprio(0);

      float rs = 0.f;
#pragma unroll
      for (int r = 0; r < 16; ++r) {
        s0[r] = __builtin_amdgcn_exp2f(s0[r]);
        s1[r] = __builtin_amdgcn_exp2f(s1[r]);
        rs += s0[r];
        rs += s1[r];
      }
      lsum += rs;

      u32 w0[8], w1[8];
#pragma unroll
      for (int b = 0; b < 4; ++b)
#pragma unroll
        for (int e = 0; e < 2; ++e) {
          w0[b * 2 + e] = cvt_pk_bf16(s0[4 * b + 2 * e], s0[4 * b + 2 * e + 1]);
          w1[b * 2 + e] = cvt_pk_bf16(s1[4 * b + 2 * e], s1[4 * b + 2 * e + 1]);
        }

      bf16x8 pa[4];
#pragma unroll
      for (int c = 0; c < 2; ++c) {
        u32 a0 = w0[(2 * c) * 2 + 0], b0 = w0[(2 * c + 1) * 2 + 0];
        u32 a1 = w0[(2 * c) * 2 + 1], b1 = w0[(2 * c + 1) * 2 + 1];
        asm("v_permlane32_swap_b32 %0, %1" : "+v"(a0), "+v"(b0));
        asm("v_permlane32_swap_b32 %0, %1" : "+v"(a1), "+v"(b1));
        const uint4 f = {a0, a1, b0, b1};
        pa[c] = __builtin_bit_cast(bf16x8, f);
      }
#pragma unroll
      for (int c = 0; c < 2; ++c) {
        u32 a0 = w1[(2 * c) * 2 + 0], b0 = w1[(2 * c + 1) * 2 + 0];
        u32 a1 = w1[(2 * c) * 2 + 1], b1 = w1[(2 * c + 1) * 2 + 1];
        asm("v_permlane32_swap_b32 %0, %1" : "+v"(a0), "+v"(b0));
        asm("v_permlane32_swap_b32 %0, %1" : "+v"(a1), "+v"(b1));
        const uint4 f = {a0, a1, b0, b1};
        pa[2 + c] = __builtin_bit_cast(bf16x8, f);
      }

      __builtin_amdgcn_s_setprio(1);
#pragma unroll
      for (int c = 0; c < 4; ++c) {
        const bf16x8 v0f = *(const bf16x8*)&Vs[lq][ko + c * 16 + h * 8];
        const bf16x8 v1f = *(const bf16x8*)&Vs[32 + lq][ko + c * 16 + h * 8];
        o0 = MFMA32(pa[c], v0f, o0);
        o1 = MFMA32(pa[c], v1f, o1);
      }
      __builtin_amdgcn_s_setprio(0);
    }
  }

  lsum += __shfl_xor(lsum, 32);

  const int bb = head >> 4, hh = head & 15;
  const float linv = 1.0f / lsum;
#pragma unroll
  for (int r = 0; r < 16; ++r) {
    const int qr = (r & 3) + 8 * (r >> 2) + 4 * h;
    const float li = __shfl(linv, qr);
    const int qg = q0 + w * 32 + qr;
    const size_t base = ((size_t)(bb * 2048 + qg)) * 1024 + hh * 64;
    Att[base + lq] = f2bf(o0[r] * li);
    Att[base + 32 + lq] = f2bf(o1[r] * li);
  }
}

// ---------------------------------------------------------------------------
// Output GEMM: R13-proven BK=64 2-buffer counted-vmcnt template, m-fastest
// grid. out = Att @ WoB^T + bo (f32 out).
// ---------------------------------------------------------------------------
__global__ __launch_bounds__(256) void out_gemm_bf(
    const u16* __restrict__ Att, const u16* __restrict__ WoB,
    const float* __restrict__ bo, float* __restrict__ out) {
  __shared__ u16 As[2][128 * 64];
  __shared__ u16 Bs[2][128 * 64];
  const int m0 = blockIdx.x * 128, n0 = blockIdx.y * 128;
  const int tid = threadIdx.x;
  const int w = tid >> 6, lane = tid & 63;
  const int wr = w >> 1, wc = w & 1;
  const int lr = lane & 15, hq = lane >> 4;

  const int srow = w * 8 + (lane >> 3);
  const int scol = ((lane & 7) ^ ((lane >> 3) & 7)) * 8;
  const u16* ag = Att + (size_t)(m0 + srow) * 1024 + scol;
  const u16* bg = WoB + (size_t)(n0 + srow) * 1024 + scol;

  f32x4 acc[4][4];
  const f32x4 fzero = {0.f, 0.f, 0.f, 0.f};
#pragma unroll
  for (int m = 0; m < 4; ++m)
#pragma unroll
    for (int n = 0; n < 4; ++n) acc[m][n] = fzero;

#define OSTAGE(b, t)                                                          \
  {                                                                           \
    _Pragma("unroll") for (int c = 0; c < 4; ++c) {                           \
      gl_lds16(ag + (size_t)c * 32 * 1024 + (t) * 64,                         \
               &As[b][c * 2048 + w * 512]);                                   \
      gl_lds16(bg + (size_t)c * 32 * 1024 + (t) * 64,                         \
               &Bs[b][c * 2048 + w * 512]);                                   \
    }                                                                         \
  }

  OSTAGE(0, 0);

#pragma unroll
  for (int t = 0; t < 16; ++t) {
    const int cur = t & 1;
    if (t < 15) {
      OSTAGE(cur ^ 1, t + 1);
      WAITV(8);
    } else {
      WAITV(0);
    }
    __builtin_amdgcn_s_barrier();
    __builtin_amdgcn_sched_barrier(0);
    __builtin_amdgcn_s_setprio(1);
#pragma unroll
    for (int kk = 0; kk < 2; ++kk) {
      bf16x8 a[4], b[4];
#pragma unroll
      for (int m = 0; m < 4; ++m) {
        const int row = wr * 64 + m * 16 + lr;
        a[m] = *(const bf16x8*)&As[cur][row * 64 + (((kk * 4 + hq) ^ (lr & 7)) * 8)];
      }
#pragma unroll
      for (int n = 0; n < 4; ++n) {
        const int row = wc * 64 + n * 16 + lr;
        b[n] = *(const bf16x8*)&Bs[cur][row * 64 + (((kk * 4 + hq) ^ (lr & 7)) * 8)];
      }
#pragma unroll
      for (int m = 0; m < 4; ++m)
#pragma unroll
        for (int n = 0; n < 4; ++n) acc[m][n] = MFMA(a[m], b[n], acc[m][n]);
    }
    __builtin_amdgcn_s_setprio(0);
    __builtin_amdgcn_sched_barrier(0);
    __builtin_amdgcn_s_barrier();
  }
#undef OSTAGE

#pragma unroll
  for (int n = 0; n < 4; ++n) {
    const int col = n0 + wc * 64 + n * 16 + lr;
    const float bvv = bo[col];
#pragma unroll
    for (int m = 0; m < 4; ++m)
#pragma unroll
      for (int j = 0; j < 4; ++j) {
        const int rowg = m0 + wr * 64 + m * 16 + hq * 4 + j;
        out[(size_t)rowg * 1024 + col] = acc[m][n][j] + bvv;
      }
  }
}

// ---------------------------------------------------------------------------
// FALLBACK output GEMM: f32 Wo converted in staging, barrier staging.
// ---------------------------------------------------------------------------
__global__ __launch_bounds__(256) void out_gemm_f32(
    const u16* __restrict__ Att, const float* __restrict__ Wo,
    const float* __restrict__ bo, float* __restrict__ out) {
  __shared__ u16 As[128][40], Bs[128][40];
  const int tid = threadIdx.x;
  const int m0 = blockIdx.y * 128, n0 = blockIdx.x * 128;
  const int w = tid >> 6, lane = tid & 63;
  const int wr = w >> 1, wc = w & 1;
  const int lr = lane & 15, lk = (lane >> 4) * 8;
  const int arow = tid >> 2, ac8 = (tid & 3) * 8;
  const int wrow = tid >> 3, wc4 = (tid & 7) * 4;

  f32x4 acc[4][4];
  const f32x4 fzero = {0.f, 0.f, 0.f, 0.f};
#pragma unroll
  for (int m = 0; m < 4; ++m)
#pragma unroll
    for (int n = 0; n < 4; ++n) acc[m][n] = fzero;

  for (int kt = 0; kt < 32; ++kt) {
    const int k0 = kt * 32;
    __syncthreads();
#pragma unroll
    for (int c = 0; c < 2; ++c) {
      *(uint4*)&As[c * 64 + arow][ac8] =
          *(const uint4*)(Att + (size_t)(m0 + c * 64 + arow) * 1024 + k0 + ac8);
    }
#pragma unroll
    for (int c = 0; c < 4; ++c) {
      const float4 wv = *(const float4*)(Wo + (size_t)(n0 + c * 32 + wrow) * 1024 + k0 + wc4);
      u16x4 hv;
      hv[0] = f2bf(wv.x); hv[1] = f2bf(wv.y); hv[2] = f2bf(wv.z); hv[3] = f2bf(wv.w);
      *(u16x4*)&Bs[c * 32 + wrow][wc4] = hv;
    }
    __syncthreads();
    bf16x8 a[4], b[4];
#pragma unroll
    for (int m = 0; m < 4; ++m)
      a[m] = *(const bf16x8*)&As[wr * 64 + m * 16 + lr][lk];
#pragma unroll
    for (int n = 0; n < 4; ++n)
      b[n] = *(const bf16x8*)&Bs[wc * 64 + n * 16 + lr][lk];
#pragma unroll
    for (int m = 0; m < 4; ++m)
#pragma unroll
      for (int n = 0; n < 4; ++n) acc[m][n] = MFMA(a[m], b[n], acc[m][n]);
  }

#pragma unroll
  for (int n = 0; n < 4; ++n) {
    const int col = n0 + wc * 64 + n * 16 + lr;
    const float bvv = bo[col];
#pragma unroll
    for (int m = 0; m < 4; ++m)
#pragma unroll
      for (int j = 0; j < 4; ++j) {
        const int rowg = m0 + wr * 64 + m * 16 + (lane >> 4) * 4 + j;
        out[(size_t)rowg * 1024 + col] = acc[m][n][j] + bvv;
      }
  }
}

// ---------------------------------------------------------------------------
extern "C" void kernel_launch(void* const* d_in, const int* in_sizes, int n_in,
                              void* d_out, int out_size, void* d_ws, size_t ws_size,
                              hipStream_t stream) {
  const float* q  = (const float*)d_in[0];
  const float* k  = (const float*)d_in[1];
  const float* v  = (const float*)d_in[2];
  const float* Wq = (const float*)d_in[3];
  const float* bq = (const float*)d_in[4];
  const float* Wk = (const float*)d_in[5];
  const float* bk = (const float*)d_in[6];
  const float* Wv = (const float*)d_in[7];
  const float* bv = (const float*)d_in[8];
  const float* Wo = (const float*)d_in[9];
  const float* bo = (const float*)d_in[10];

  u16* ws  = (u16*)d_ws;
  u16* Qh  = ws;
  u16* Kh  = ws + (size_t)8388608;
  u16* Vt  = ws + (size_t)16777216;
  u16* Att = ws + (size_t)25165824;   // overlaps Xb[q] (attn runs after proj)
  u16* Xb  = ws + (size_t)25165824;   // 3 x 8388608
  u16* Wb  = ws + (size_t)50331648;   // 3 x 1048576
  u16* WoB = ws + (size_t)53477376;
  const size_t need = (size_t)55574528 * 2;

  if (ws_size >= need) {
    cvt_all<<<dim3(14336), dim3(256), 0, stream>>>(q, k, v, Wq, Wk, Wv, Wo, Xb,
                                                   Wb, WoB);
    proj_gemm_bf<<<dim3(32, 4, 3), dim3(512), 0, stream>>>(Xb, Wb, bq, bk, bv,
                                                           Qh, Kh, Vt);
    attn_fwd<<<dim3(64, 8), dim3(512), 0, stream>>>(Qh, Kh, Vt, Att);
    out_gemm_bf<<<dim3(64, 8), dim3(256), 0, stream>>>(Att, WoB, bo,
                                                       (float*)d_out);
  } else {
    proj_gemm_f32<<<dim3(8, 64, 3), dim3(256), 0, stream>>>(
        q, k, v, Wq, Wk, Wv, bq, bk, bv, Qh, Kh, Vt);
    attn_fwd<<<dim3(64, 8), dim3(512), 0, stream>>>(Qh, Kh, Vt, Att);
    out_gemm_f32<<<dim3(8, 64), dim3(256), 0, stream>>>(Att, Wo, bo,
                                                        (float*)d_out);
  }
}

// Round 21
// 190.559 us; speedup vs baseline: 1.2081x; 1.2081x over previous
//
#include <hip/hip_runtime.h>
#include <cstdint>

using u16 = unsigned short;
using u32 = unsigned int;
typedef __bf16 bf16x8 __attribute__((ext_vector_type(8)));
typedef float f32x4 __attribute__((ext_vector_type(4)));
typedef float f32x16 __attribute__((ext_vector_type(16)));
typedef u16 u16x8 __attribute__((ext_vector_type(8)));
typedef u16 u16x4 __attribute__((ext_vector_type(4)));

#define DEV static __device__ __forceinline__

DEV u16 f2bf(float f) {
  uint32_t u = __builtin_bit_cast(uint32_t, f);
  u += 0x7FFFu + ((u >> 16) & 1u);
  return (u16)(u >> 16);
}
DEV float bf2f(u16 h) {
  uint32_t u = ((uint32_t)h) << 16;
  return __builtin_bit_cast(float, u);
}
DEV u32 cvt_pk_bf16(float lo, float hi) {  // attn only (T12 pattern)
  u32 r;
  asm("v_cvt_pk_bf16_f32 %0, %1, %2" : "=v"(r) : "v"(lo), "v"(hi));
  return r;
}

typedef const u32 __attribute__((address_space(1))) gcu32;
typedef u32 __attribute__((address_space(3))) lu32;
DEV void gl_lds16(const u16* g, u16* l) {
  __builtin_amdgcn_global_load_lds((gcu32*)g, (lu32*)l, 16, 0, 0);
}

#define MFMA(a, b, c) __builtin_amdgcn_mfma_f32_16x16x32_bf16((a), (b), (c), 0, 0, 0)
#define MFMA32(a, b, c) __builtin_amdgcn_mfma_f32_32x32x16_bf16((a), (b), (c), 0, 0, 0)

#define WAITV(n) asm volatile("s_waitcnt vmcnt(" #n ")" ::: "memory")

// ---------------------------------------------------------------------------
// Fused conversion pass: f32 -> bf16 once, outside the GEMM hot loops.
// ---------------------------------------------------------------------------
__global__ __launch_bounds__(256) void cvt_all(
    const float* __restrict__ q, const float* __restrict__ k,
    const float* __restrict__ v, const float* __restrict__ Wq,
    const float* __restrict__ Wk, const float* __restrict__ Wv,
    const float* __restrict__ Wo, u16* __restrict__ Xb, u16* __restrict__ Wb,
    u16* __restrict__ WoB) {
  const int bid = blockIdx.x;
  const float* src;
  u16* dst;
  size_t i;
  if (bid < 12288) {
    const int z = bid >> 12;
    src = (z == 0) ? q : (z == 1) ? k : v;
    dst = Xb + (size_t)z * 8388608;
    i = ((size_t)(bid & 4095) * 256 + threadIdx.x) * 8;
  } else {
    const int r = bid - 12288;
    const int z = r >> 9;
    src = (z == 0) ? Wq : (z == 1) ? Wk : (z == 2) ? Wv : Wo;
    dst = (z < 3) ? (Wb + (size_t)z * 1048576) : WoB;
    i = ((size_t)(r & 511) * 256 + threadIdx.x) * 8;
  }
  const float4 a = *(const float4*)(src + i);
  const float4 b = *(const float4*)(src + i + 4);
  u16x8 o;
  o[0] = f2bf(a.x); o[1] = f2bf(a.y); o[2] = f2bf(a.z); o[3] = f2bf(a.w);
  o[4] = f2bf(b.x); o[5] = f2bf(b.y); o[6] = f2bf(b.z); o[7] = f2bf(b.w);
  *(u16x8*)(dst + i) = o;
}

// ---------------------------------------------------------------------------
// Pure-bf16 fused projection GEMM (R13/R18-proven best). 128x128 tile,
// 4 waves, BK=64, 2-buffer counted-vmcnt pipeline, m-fastest grid
// (XCD = m%8), source-swizzle (conflicts = 0). z = 0:Q, 1:K, 2:V.
// Output bf16: z<2 -> out[(b*16+h)*2048+s][d]; z=2 -> out[(b*16+h)*64+d][s].
// Q epilogue folds oscale = (1/8)*log2(e) (attn works in log2 domain).
// Structural bets tried and rejected by measurement: fat wave tile (R11/R20,
// occupancy/spill), B-bypass (R16 race / R17 uncoalesced), depth-2 prefetch
// (R19, latency not binding). This 2-phase counted-vmcnt form is the
// empirical plateau (~26% MfmaUtil).
// ---------------------------------------------------------------------------
__global__ __launch_bounds__(256) void proj_gemm_bf(
    const u16* __restrict__ Xb, const u16* __restrict__ Wb,
    const float* __restrict__ bq, const float* __restrict__ bk,
    const float* __restrict__ bv, u16* __restrict__ Qh, u16* __restrict__ Kh,
    u16* __restrict__ Vt) {
  __shared__ u16 As[2][128 * 64];  // 2 x 16KB
  __shared__ u16 Bs[2][128 * 64];  // 2 x 16KB
  const int z = blockIdx.z;
  const int m0 = blockIdx.x * 128, n0 = blockIdx.y * 128;

  const u16* x = Xb + (size_t)z * 8388608;
  const u16* W = Wb + (size_t)z * 1048576;
  const float* bias = (z == 0) ? bq : (z == 1) ? bk : bv;
  u16* out = (z == 0) ? Qh : (z == 1) ? Kh : Vt;
  const float oscale = (z == 0) ? 0.18033688011112042f : 1.0f;

  const int tid = threadIdx.x;
  const int w = tid >> 6, lane = tid & 63;
  const int wr = w >> 1, wc = w & 1;
  const int lr = lane & 15, hq = lane >> 4;

  const int srow = w * 8 + (lane >> 3);
  const int scol = ((lane & 7) ^ ((lane >> 3) & 7)) * 8;
  const u16* xg = x + (size_t)(m0 + srow) * 1024 + scol;
  const u16* wg_ = W + (size_t)(n0 + srow) * 1024 + scol;

  f32x4 acc[4][4];
  const f32x4 fzero = {0.f, 0.f, 0.f, 0.f};
#pragma unroll
  for (int m = 0; m < 4; ++m)
#pragma unroll
    for (int n = 0; n < 4; ++n) acc[m][n] = fzero;

#define PSTAGE(b, t)                                                          \
  {                                                                           \
    _Pragma("unroll") for (int c = 0; c < 4; ++c) {                           \
      gl_lds16(xg + (size_t)c * 32 * 1024 + (t) * 64,                         \
               &As[b][c * 2048 + w * 512]);                                   \
      gl_lds16(wg_ + (size_t)c * 32 * 1024 + (t) * 64,                        \
               &Bs[b][c * 2048 + w * 512]);                                   \
    }                                                                         \
  }

  PSTAGE(0, 0);

#pragma unroll
  for (int t = 0; t < 16; ++t) {
    const int cur = t & 1;
    if (t < 15) {
      PSTAGE(cur ^ 1, t + 1);
      WAITV(8);
    } else {
      WAITV(0);
    }
    __builtin_amdgcn_s_barrier();
    __builtin_amdgcn_sched_barrier(0);
    __builtin_amdgcn_s_setprio(1);
#pragma unroll
    for (int kk = 0; kk < 2; ++kk) {
      bf16x8 a[4], b[4];
#pragma unroll
      for (int m = 0; m < 4; ++m) {
        const int row = wr * 64 + m * 16 + lr;
        a[m] = *(const bf16x8*)&As[cur][row * 64 + (((kk * 4 + hq) ^ (lr & 7)) * 8)];
      }
#pragma unroll
      for (int n = 0; n < 4; ++n) {
        const int row = wc * 64 + n * 16 + lr;
        b[n] = *(const bf16x8*)&Bs[cur][row * 64 + (((kk * 4 + hq) ^ (lr & 7)) * 8)];
      }
#pragma unroll
      for (int m = 0; m < 4; ++m)
#pragma unroll
        for (int n = 0; n < 4; ++n) acc[m][n] = MFMA(a[m], b[n], acc[m][n]);
    }
    __builtin_amdgcn_s_setprio(0);
    __builtin_amdgcn_sched_barrier(0);
    __builtin_amdgcn_s_barrier();
  }
#undef PSTAGE

#pragma unroll
  for (int n = 0; n < 4; ++n) {
    const int col = n0 + wc * 64 + n * 16 + lr;
    const float bvv = bias[col];
    const int h = col >> 6, d = col & 63;
#pragma unroll
    for (int m = 0; m < 4; ++m) {
#pragma unroll
      for (int j = 0; j < 4; ++j) {
        const int rowg = m0 + wr * 64 + m * 16 + hq * 4 + j;
        const int bb = rowg >> 11, s = rowg & 2047;
        const float val = (acc[m][n][j] + bvv) * oscale;
        size_t idx;
        if (z != 2)
          idx = ((size_t)(bb * 16 + h) * 2048 + s) * 64 + d;
        else
          idx = ((size_t)(bb * 16 + h) * 64 + d) * 2048 + s;
        out[idx] = f2bf(val);
      }
    }
  }
}

// ---------------------------------------------------------------------------
// FALLBACK projection GEMM (f32 inputs, barrier staging). Used only when
// ws_size is too small for the bf16 conversion workspace.
// ---------------------------------------------------------------------------
__global__ __launch_bounds__(256) void proj_gemm_f32(
    const float* __restrict__ q, const float* __restrict__ k,
    const float* __restrict__ v, const float* __restrict__ Wq,
    const float* __restrict__ Wk, const float* __restrict__ Wv,
    const float* __restrict__ bq, const float* __restrict__ bk,
    const float* __restrict__ bv, u16* __restrict__ Qh, u16* __restrict__ Kh,
    u16* __restrict__ Vt) {
  __shared__ u16 As[128][40];
  __shared__ u16 Bs[128][40];
  const int z = blockIdx.z;
  const float* x = (z == 0) ? q : (z == 1) ? k : v;
  const float* W = (z == 0) ? Wq : (z == 1) ? Wk : Wv;
  const float* bias = (z == 0) ? bq : (z == 1) ? bk : bv;
  u16* out = (z == 0) ? Qh : (z == 1) ? Kh : Vt;
  const float oscale = (z == 0) ? 0.18033688011112042f : 1.0f;

  const int tid = threadIdx.x;
  const int m0 = blockIdx.y * 128, n0 = blockIdx.x * 128;
  const int w = tid >> 6, lane = tid & 63;
  const int wr = w >> 1, wc = w & 1;
  const int lr = lane & 15, lk = (lane >> 4) * 8;
  const int srow = tid >> 3, sc4 = (tid & 7) * 4;

  f32x4 acc[4][4];
  const f32x4 fzero = {0.f, 0.f, 0.f, 0.f};
#pragma unroll
  for (int m = 0; m < 4; ++m)
#pragma unroll
    for (int n = 0; n < 4; ++n) acc[m][n] = fzero;

  for (int kt = 0; kt < 32; ++kt) {
    const int k0 = kt * 32;
    __syncthreads();
#pragma unroll
    for (int c = 0; c < 4; ++c) {
      const float4 av = *(const float4*)(x + (size_t)(m0 + c * 32 + srow) * 1024 + k0 + sc4);
      const float4 bvv = *(const float4*)(W + (size_t)(n0 + c * 32 + srow) * 1024 + k0 + sc4);
      u16x4 ah, bh;
      ah[0] = f2bf(av.x); ah[1] = f2bf(av.y); ah[2] = f2bf(av.z); ah[3] = f2bf(av.w);
      bh[0] = f2bf(bvv.x); bh[1] = f2bf(bvv.y); bh[2] = f2bf(bvv.z); bh[3] = f2bf(bvv.w);
      *(u16x4*)&As[c * 32 + srow][sc4] = ah;
      *(u16x4*)&Bs[c * 32 + srow][sc4] = bh;
    }
    __syncthreads();
    bf16x8 a[4], b[4];
#pragma unroll
    for (int m = 0; m < 4; ++m)
      a[m] = *(const bf16x8*)&As[wr * 64 + m * 16 + lr][lk];
#pragma unroll
    for (int n = 0; n < 4; ++n)
      b[n] = *(const bf16x8*)&Bs[wc * 64 + n * 16 + lr][lk];
#pragma unroll
    for (int m = 0; m < 4; ++m)
#pragma unroll
      for (int n = 0; n < 4; ++n) acc[m][n] = MFMA(a[m], b[n], acc[m][n]);
  }

#pragma unroll
  for (int n = 0; n < 4; ++n) {
    const int col = n0 + wc * 64 + n * 16 + lr;
    const float bvv = bias[col];
    const int h = col >> 6, d = col & 63;
#pragma unroll
    for (int m = 0; m < 4; ++m) {
#pragma unroll
      for (int j = 0; j < 4; ++j) {
        const int rowg = m0 + wr * 64 + m * 16 + (lane >> 4) * 4 + j;
        const int bb = rowg >> 11, s = rowg & 2047;
        const float val = (acc[m][n][j] + bvv) * oscale;
        size_t idx;
        if (z != 2)
          idx = ((size_t)(bb * 16 + h) * 2048 + s) * 64 + d;
        else
          idx = ((size_t)(bb * 16 + h) * 64 + d) * 2048 + s;
        out[idx] = f2bf(val);
      }
    }
  }
}

// ---------------------------------------------------------------------------
// Flash attention (R15-proven): KVBLK=128, no osum MFMA (row-sum on VALU,
// lane-local by q=lq, one shfl_xor(32) after the KV loop). PV output
// o0[r] = D[q=crow(r,h)][d=lq]; per-row 1/sum via __shfl(linv, qr).
// 8 waves x 32 q-rows = 256 q per block. Output bf16 [b*2048+s][h*64+d].
// ---------------------------------------------------------------------------
__global__ __launch_bounds__(512, 4) void attn_fwd(
    const u16* __restrict__ Qh, const u16* __restrict__ Kh,
    const u16* __restrict__ Vt, u16* __restrict__ Att) {
  __shared__ u16 Ks[128][72];   // K rows (kv), 64 d + pad
  __shared__ u16 Vs[64][136];   // V^T: d rows, 128 s + pad
  const int tid = threadIdx.x;
  const int w = tid >> 6, lane = tid & 63;
  const int lq = lane & 31, h = lane >> 5;
  const int head = blockIdx.x, q0 = blockIdx.y * 256;
  const u16* Qb = Qh + (size_t)head * 131072;
  const u16* Kb = Kh + (size_t)head * 131072;
  const u16* Vb = Vt + (size_t)head * 131072;
  const int qrow = q0 + w * 32 + lq;

  bf16x8 qf[4];
#pragma unroll
  for (int dc = 0; dc < 4; ++dc)
    qf[dc] = *(const bf16x8*)(Qb + (size_t)qrow * 64 + dc * 16 + h * 8);

  f32x16 o0 = {}, o1 = {};
  float lsum = 0.f;

  const int srow = tid >> 3, scol = (tid & 7) * 8;
  uint4 kr0, kr1, vr0, vr1;
  kr0 = *(const uint4*)(Kb + (size_t)srow * 64 + scol);
  kr1 = *(const uint4*)(Kb + (size_t)(64 + srow) * 64 + scol);
  vr0 = *(const uint4*)(Vb + (size_t)srow * 2048 + scol);
  vr1 = *(const uint4*)(Vb + (size_t)srow * 2048 + 64 + scol);

  for (int kt = 0; kt < 16; ++kt) {
    __syncthreads();
    *(uint4*)&Ks[srow][scol] = kr0;
    *(uint4*)&Ks[64 + srow][scol] = kr1;
    *(uint4*)&Vs[srow][scol] = vr0;
    *(uint4*)&Vs[srow][64 + scol] = vr1;
    __syncthreads();
    if (kt + 1 < 16) {
      const int t0n = (kt + 1) * 128;
      kr0 = *(const uint4*)(Kb + (size_t)(t0n + srow) * 64 + scol);
      kr1 = *(const uint4*)(Kb + (size_t)(t0n + 64 + srow) * 64 + scol);
      vr0 = *(const uint4*)(Vb + (size_t)srow * 2048 + t0n + scol);
      vr1 = *(const uint4*)(Vb + (size_t)srow * 2048 + t0n + 64 + scol);
    }

#pragma unroll
    for (int half = 0; half < 2; ++half) {
      const int ko = half * 64;

      f32x16 s0 = {}, s1 = {};
      __builtin_amdgcn_s_setprio(1);
#pragma unroll
      for (int dc = 0; dc < 4; ++dc) {
        const bf16x8 k0 = *(const bf16x8*)&Ks[ko + lq][dc * 16 + h * 8];
        const bf16x8 k1 = *(const bf16x8*)&Ks[ko + 32 + lq][dc * 16 + h * 8];
        s0 = MFMA32(k0, qf[dc], s0);
        s1 = MFMA32(k1, qf[dc], s1);
      }
      __builtin_amdgcn_s_setprio(0);

      float rs = 0.f;
#pragma unroll
      for (int r = 0; r < 16; ++r) {
        s0[r] = __builtin_amdgcn_exp2f(s0[r]);
        s1[r] = __builtin_amdgcn_exp2f(s1[r]);
        rs += s0[r];
        rs += s1[r];
      }
      lsum += rs;

      u32 w0[8], w1[8];
#pragma unroll
      for (int b = 0; b < 4; ++b)
#pragma unroll
        for (int e = 0; e < 2; ++e) {
          w0[b * 2 + e] = cvt_pk_bf16(s0[4 * b + 2 * e], s0[4 * b + 2 * e + 1]);
          w1[b * 2 + e] = cvt_pk_bf16(s1[4 * b + 2 * e], s1[4 * b + 2 * e + 1]);
        }

      bf16x8 pa[4];
#pragma unroll
      for (int c = 0; c < 2; ++c) {
        u32 a0 = w0[(2 * c) * 2 + 0], b0 = w0[(2 * c + 1) * 2 + 0];
        u32 a1 = w0[(2 * c) * 2 + 1], b1 = w0[(2 * c + 1) * 2 + 1];
        asm("v_permlane32_swap_b32 %0, %1" : "+v"(a0), "+v"(b0));
        asm("v_permlane32_swap_b32 %0, %1" : "+v"(a1), "+v"(b1));
        const uint4 f = {a0, a1, b0, b1};
        pa[c] = __builtin_bit_cast(bf16x8, f);
      }
#pragma unroll
      for (int c = 0; c < 2; ++c) {
        u32 a0 = w1[(2 * c) * 2 + 0], b0 = w1[(2 * c + 1) * 2 + 0];
        u32 a1 = w1[(2 * c) * 2 + 1], b1 = w1[(2 * c + 1) * 2 + 1];
        asm("v_permlane32_swap_b32 %0, %1" : "+v"(a0), "+v"(b0));
        asm("v_permlane32_swap_b32 %0, %1" : "+v"(a1), "+v"(b1));
        const uint4 f = {a0, a1, b0, b1};
        pa[2 + c] = __builtin_bit_cast(bf16x8, f);
      }

      __builtin_amdgcn_s_setprio(1);
#pragma unroll
      for (int c = 0; c < 4; ++c) {
        const bf16x8 v0f = *(const bf16x8*)&Vs[lq][ko + c * 16 + h * 8];
        const bf16x8 v1f = *(const bf16x8*)&Vs[32 + lq][ko + c * 16 + h * 8];
        o0 = MFMA32(pa[c], v0f, o0);
        o1 = MFMA32(pa[c], v1f, o1);
      }
      __builtin_amdgcn_s_setprio(0);
    }
  }

  lsum += __shfl_xor(lsum, 32);

  const int bb = head >> 4, hh = head & 15;
  const float linv = 1.0f / lsum;
#pragma unroll
  for (int r = 0; r < 16; ++r) {
    const int qr = (r & 3) + 8 * (r >> 2) + 4 * h;
    const float li = __shfl(linv, qr);
    const int qg = q0 + w * 32 + qr;
    const size_t base = ((size_t)(bb * 2048 + qg)) * 1024 + hh * 64;
    Att[base + lq] = f2bf(o0[r] * li);
    Att[base + 32 + lq] = f2bf(o1[r] * li);
  }
}

// ---------------------------------------------------------------------------
// Output GEMM: R13-proven BK=64 2-buffer counted-vmcnt template, m-fastest
// grid. out = Att @ WoB^T + bo (f32 out).
// ---------------------------------------------------------------------------
__global__ __launch_bounds__(256) void out_gemm_bf(
    const u16* __restrict__ Att, const u16* __restrict__ WoB,
    const float* __restrict__ bo, float* __restrict__ out) {
  __shared__ u16 As[2][128 * 64];
  __shared__ u16 Bs[2][128 * 64];
  const int m0 = blockIdx.x * 128, n0 = blockIdx.y * 128;
  const int tid = threadIdx.x;
  const int w = tid >> 6, lane = tid & 63;
  const int wr = w >> 1, wc = w & 1;
  const int lr = lane & 15, hq = lane >> 4;

  const int srow = w * 8 + (lane >> 3);
  const int scol = ((lane & 7) ^ ((lane >> 3) & 7)) * 8;
  const u16* ag = Att + (size_t)(m0 + srow) * 1024 + scol;
  const u16* bg = WoB + (size_t)(n0 + srow) * 1024 + scol;

  f32x4 acc[4][4];
  const f32x4 fzero = {0.f, 0.f, 0.f, 0.f};
#pragma unroll
  for (int m = 0; m < 4; ++m)
#pragma unroll
    for (int n = 0; n < 4; ++n) acc[m][n] = fzero;

#define OSTAGE(b, t)                                                          \
  {                                                                           \
    _Pragma("unroll") for (int c = 0; c < 4; ++c) {                           \
      gl_lds16(ag + (size_t)c * 32 * 1024 + (t) * 64,                         \
               &As[b][c * 2048 + w * 512]);                                   \
      gl_lds16(bg + (size_t)c * 32 * 1024 + (t) * 64,                         \
               &Bs[b][c * 2048 + w * 512]);                                   \
    }                                                                         \
  }

  OSTAGE(0, 0);

#pragma unroll
  for (int t = 0; t < 16; ++t) {
    const int cur = t & 1;
    if (t < 15) {
      OSTAGE(cur ^ 1, t + 1);
      WAITV(8);
    } else {
      WAITV(0);
    }
    __builtin_amdgcn_s_barrier();
    __builtin_amdgcn_sched_barrier(0);
    __builtin_amdgcn_s_setprio(1);
#pragma unroll
    for (int kk = 0; kk < 2; ++kk) {
      bf16x8 a[4], b[4];
#pragma unroll
      for (int m = 0; m < 4; ++m) {
        const int row = wr * 64 + m * 16 + lr;
        a[m] = *(const bf16x8*)&As[cur][row * 64 + (((kk * 4 + hq) ^ (lr & 7)) * 8)];
      }
#pragma unroll
      for (int n = 0; n < 4; ++n) {
        const int row = wc * 64 + n * 16 + lr;
        b[n] = *(const bf16x8*)&Bs[cur][row * 64 + (((kk * 4 + hq) ^ (lr & 7)) * 8)];
      }
#pragma unroll
      for (int m = 0; m < 4; ++m)
#pragma unroll
        for (int n = 0; n < 4; ++n) acc[m][n] = MFMA(a[m], b[n], acc[m][n]);
    }
    __builtin_amdgcn_s_setprio(0);
    __builtin_amdgcn_sched_barrier(0);
    __builtin_amdgcn_s_barrier();
  }
#undef OSTAGE

#pragma unroll
  for (int n = 0; n < 4; ++n) {
    const int col = n0 + wc * 64 + n * 16 + lr;
    const float bvv = bo[col];
#pragma unroll
    for (int m = 0; m < 4; ++m)
#pragma unroll
      for (int j = 0; j < 4; ++j) {
        const int rowg = m0 + wr * 64 + m * 16 + hq * 4 + j;
        out[(size_t)rowg * 1024 + col] = acc[m][n][j] + bvv;
      }
  }
}

// ---------------------------------------------------------------------------
// FALLBACK output GEMM: f32 Wo converted in staging, barrier staging.
// ---------------------------------------------------------------------------
__global__ __launch_bounds__(256) void out_gemm_f32(
    const u16* __restrict__ Att, const float* __restrict__ Wo,
    const float* __restrict__ bo, float* __restrict__ out) {
  __shared__ u16 As[128][40], Bs[128][40];
  const int tid = threadIdx.x;
  const int m0 = blockIdx.y * 128, n0 = blockIdx.x * 128;
  const int w = tid >> 6, lane = tid & 63;
  const int wr = w >> 1, wc = w & 1;
  const int lr = lane & 15, lk = (lane >> 4) * 8;
  const int arow = tid >> 2, ac8 = (tid & 3) * 8;
  const int wrow = tid >> 3, wc4 = (tid & 7) * 4;

  f32x4 acc[4][4];
  const f32x4 fzero = {0.f, 0.f, 0.f, 0.f};
#pragma unroll
  for (int m = 0; m < 4; ++m)
#pragma unroll
    for (int n = 0; n < 4; ++n) acc[m][n] = fzero;

  for (int kt = 0; kt < 32; ++kt) {
    const int k0 = kt * 32;
    __syncthreads();
#pragma unroll
    for (int c = 0; c < 2; ++c) {
      *(uint4*)&As[c * 64 + arow][ac8] =
          *(const uint4*)(Att + (size_t)(m0 + c * 64 + arow) * 1024 + k0 + ac8);
    }
#pragma unroll
    for (int c = 0; c < 4; ++c) {
      const float4 wv = *(const float4*)(Wo + (size_t)(n0 + c * 32 + wrow) * 1024 + k0 + wc4);
      u16x4 hv;
      hv[0] = f2bf(wv.x); hv[1] = f2bf(wv.y); hv[2] = f2bf(wv.z); hv[3] = f2bf(wv.w);
      *(u16x4*)&Bs[c * 32 + wrow][wc4] = hv;
    }
    __syncthreads();
    bf16x8 a[4], b[4];
#pragma unroll
    for (int m = 0; m < 4; ++m)
      a[m] = *(const bf16x8*)&As[wr * 64 + m * 16 + lr][lk];
#pragma unroll
    for (int n = 0; n < 4; ++n)
      b[n] = *(const bf16x8*)&Bs[wc * 64 + n * 16 + lr][lk];
#pragma unroll
    for (int m = 0; m < 4; ++m)
#pragma unroll
      for (int n = 0; n < 4; ++n) acc[m][n] = MFMA(a[m], b[n], acc[m][n]);
  }

#pragma unroll
  for (int n = 0; n < 4; ++n) {
    const int col = n0 + wc * 64 + n * 16 + lr;
    const float bvv = bo[col];
#pragma unroll
    for (int m = 0; m < 4; ++m)
#pragma unroll
      for (int j = 0; j < 4; ++j) {
        const int rowg = m0 + wr * 64 + m * 16 + (lane >> 4) * 4 + j;
        out[(size_t)rowg * 1024 + col] = acc[m][n][j] + bvv;
      }
  }
}

// ---------------------------------------------------------------------------
extern "C" void kernel_launch(void* const* d_in, const int* in_sizes, int n_in,
                              void* d_out, int out_size, void* d_ws, size_t ws_size,
                              hipStream_t stream) {
  const float* q  = (const float*)d_in[0];
  const float* k  = (const float*)d_in[1];
  const float* v  = (const float*)d_in[2];
  const float* Wq = (const float*)d_in[3];
  const float* bq = (const float*)d_in[4];
  const float* Wk = (const float*)d_in[5];
  const float* bk = (const float*)d_in[6];
  const float* Wv = (const float*)d_in[7];
  const float* bv = (const float*)d_in[8];
  const float* Wo = (const float*)d_in[9];
  const float* bo = (const float*)d_in[10];

  u16* ws  = (u16*)d_ws;
  u16* Qh  = ws;
  u16* Kh  = ws + (size_t)8388608;
  u16* Vt  = ws + (size_t)16777216;
  u16* Att = ws + (size_t)25165824;   // overlaps Xb[q] (attn runs after proj)
  u16* Xb  = ws + (size_t)25165824;   // 3 x 8388608
  u16* Wb  = ws + (size_t)50331648;   // 3 x 1048576
  u16* WoB = ws + (size_t)53477376;
  const size_t need = (size_t)55574528 * 2;

  if (ws_size >= need) {
    cvt_all<<<dim3(14336), dim3(256), 0, stream>>>(q, k, v, Wq, Wk, Wv, Wo, Xb,
                                                   Wb, WoB);
    proj_gemm_bf<<<dim3(64, 8, 3), dim3(256), 0, stream>>>(Xb, Wb, bq, bk, bv,
                                                           Qh, Kh, Vt);
    attn_fwd<<<dim3(64, 8), dim3(512), 0, stream>>>(Qh, Kh, Vt, Att);
    out_gemm_bf<<<dim3(64, 8), dim3(256), 0, stream>>>(Att, WoB, bo,
                                                       (float*)d_out);
  } else {
    proj_gemm_f32<<<dim3(8, 64, 3), dim3(256), 0, stream>>>(
        q, k, v, Wq, Wk, Wv, bq, bk, bv, Qh, Kh, Vt);
    attn_fwd<<<dim3(64, 8), dim3(512), 0, stream>>>(Qh, Kh, Vt, Att);
    out_gemm_f32<<<dim3(8, 64), dim3(256), 0, stream>>>(Att, Wo, bo,
                                                        (float*)d_out);
  }
}